// Round 4
// baseline (792.613 us; speedup 1.0000x reference)
//
#include <hip/hip_runtime.h>
#include <math.h>

#define NB 8
#define NT1 2048
#define NT2 512
#define NC 384
#define ND 192
#define NF 1536
#define NKI 3456   // 9*384 implicit-GEMM K for conv
#define TPAD 2056  // 2048 + 4 guard rows top and bottom

typedef __attribute__((ext_vector_type(8))) short bf16x8;
typedef __attribute__((ext_vector_type(4))) float f32x4;

#define GLOAD16(gsrc, ldst) \
  __builtin_amdgcn_global_load_lds((const __attribute__((address_space(1))) void*)(gsrc), \
                                   (__attribute__((address_space(3))) void*)(ldst), 16, 0, 0)

static __device__ __forceinline__ unsigned short f2bf(float f) {
  unsigned int u = __float_as_uint(f);
  unsigned int r = (u + 0x7fffu + ((u >> 16) & 1u)) >> 16;
  return (unsigned short)r;
}

static __device__ __forceinline__ float warp_sum(float v) {
#pragma unroll
  for (int off = 32; off > 0; off >>= 1) v += __shfl_xor(v, off);
  return v;
}

// x += alpha * sin-pos; thread handles (t,j) pair: sin at c=j, cos at c=j+192
__global__ __launch_bounds__(256) void k_add_pos2(const float* __restrict__ x,
    const float* __restrict__ alpha_p, float* __restrict__ y, int T, int total2) {
  int i = blockIdx.x * 256 + threadIdx.x;
  if (i >= total2) return;
  int j = i % 192;
  int row = i / 192;
  int t = row % T;
  float freq = __expf(-0.0482216773f * (float)j);   // ln(10000)/191
  float ang = (float)(t + 1) * freq;
  float sn, cs;
  __sincosf(ang, &sn, &cs);
  float a = alpha_p[0];
  size_t base = (size_t)row * NC;
  y[base + j] = x[base + j] + a * sn;
  y[base + j + 192] = x[base + j + 192] + a * cs;
}

__global__ __launch_bounds__(256) void k_add_pos2_bf16(const float* __restrict__ x,
    const float* __restrict__ alpha_p, unsigned short* __restrict__ y, int T, int total2) {
  int i = blockIdx.x * 256 + threadIdx.x;
  if (i >= total2) return;
  int j = i % 192;
  int row = i / 192;
  int t = row % T;
  float freq = __expf(-0.0482216773f * (float)j);
  float ang = (float)(t + 1) * freq;
  float sn, cs;
  __sincosf(ang, &sn, &cs);
  float a = alpha_p[0];
  size_t base = (size_t)row * NC;
  y[base + j] = f2bf(x[base + j] + a * sn);
  y[base + j + 192] = f2bf(x[base + j + 192] + a * cs);
}

// LayerNorm over last dim (384). One wave per row. fp32 out (final LN).
__global__ __launch_bounds__(256) void k_ln(const float* __restrict__ x,
    const float* __restrict__ g, const float* __restrict__ b,
    float* __restrict__ y, int nrows) {
  int row = blockIdx.x * 4 + (threadIdx.x >> 6);
  int lane = threadIdx.x & 63;
  if (row >= nrows) return;
  const float* xr = x + (size_t)row * NC;
  float v[6];
  float s = 0.f, s2 = 0.f;
#pragma unroll
  for (int i = 0; i < 6; ++i) {
    float t = xr[lane + 64 * i];
    v[i] = t; s += t; s2 += t * t;
  }
  s = warp_sum(s); s2 = warp_sum(s2);
  float mean = s * (1.f / NC);
  float var = s2 * (1.f / NC) - mean * mean;
  float rs = rsqrtf(var + 1e-5f);
  float* yr = y + (size_t)row * NC;
#pragma unroll
  for (int i = 0; i < 6; ++i) {
    int cc = lane + 64 * i;
    yr[cc] = (v[i] - mean) * rs * g[cc] + b[cc];
  }
}

// LayerNorm -> bf16 (unpadded), feeds MFMA projections
__global__ __launch_bounds__(256) void k_ln_bf16(const float* __restrict__ x,
    const float* __restrict__ g, const float* __restrict__ b,
    unsigned short* __restrict__ y) {
  int row = blockIdx.x * 4 + (threadIdx.x >> 6);
  int lane = threadIdx.x & 63;
  const float* xr = x + (size_t)row * NC;
  float v[6];
  float s = 0.f, s2 = 0.f;
#pragma unroll
  for (int i = 0; i < 6; ++i) {
    float t = xr[lane + 64 * i];
    v[i] = t; s += t; s2 += t * t;
  }
  s = warp_sum(s); s2 = warp_sum(s2);
  float mean = s * (1.f / NC);
  float var = s2 * (1.f / NC) - mean * mean;
  float rs = rsqrtf(var + 1e-5f);
  unsigned short* yr = y + (size_t)row * NC;
#pragma unroll
  for (int i = 0; i < 6; ++i) {
    int cc = lane + 64 * i;
    yr[cc] = f2bf((v[i] - mean) * rs * g[cc] + b[cc]);
  }
}

// LayerNorm -> bf16 into guard-padded [8][2056][384] buffer (row t -> t+4)
__global__ __launch_bounds__(256) void k_ln_bf16p(const float* __restrict__ x,
    const float* __restrict__ g, const float* __restrict__ b,
    unsigned short* __restrict__ ypad) {
  int row = blockIdx.x * 4 + (threadIdx.x >> 6);
  int lane = threadIdx.x & 63;
  const float* xr = x + (size_t)row * NC;
  float v[6];
  float s = 0.f, s2 = 0.f;
#pragma unroll
  for (int i = 0; i < 6; ++i) {
    float t = xr[lane + 64 * i];
    v[i] = t; s += t; s2 += t * t;
  }
  s = warp_sum(s); s2 = warp_sum(s2);
  float mean = s * (1.f / NC);
  float var = s2 * (1.f / NC) - mean * mean;
  float rs = rsqrtf(var + 1e-5f);
  int bb = row >> 11, t = row & 2047;
  unsigned short* yr = ypad + ((size_t)(bb * TPAD + t + 4)) * NC;
#pragma unroll
  for (int i = 0; i < 6; ++i) {
    int cc = lane + 64 * i;
    yr[cc] = f2bf((v[i] - mean) * rs * g[cc] + b[cc]);
  }
}

// zero the 4 guard rows top+bottom of each batch slab in ypad
__global__ __launch_bounds__(256) void k_zero_guard(unsigned short* __restrict__ ypad) {
  int i = blockIdx.x * 256 + threadIdx.x;   // 8*8*384 = 24576
  if (i >= 24576) return;
  int c = i % NC;
  int r = (i / NC) % 8;
  int b = i / (NC * 8);
  int t = (r < 4) ? r : (2048 + r);         // rows 0..3 and 2052..2055
  ypad[((size_t)b * TPAD + t) * NC + c] = 0;
}

// pack + convert cw[f][c][kk] -> cwp[f][kk*384+c] bf16. One block per f-row,
// coalesced load -> LDS -> coalesced store (LDS read stride 9: conflict-free).
__global__ __launch_bounds__(256) void k_pack_cw2(const float* __restrict__ cw,
    unsigned short* __restrict__ cwp) {
  __shared__ float s[NKI];
  int f = blockIdx.x;
  const float* src = cw + (size_t)f * NKI;
  for (int i = threadIdx.x; i < NKI; i += 256) s[i] = src[i];
  __syncthreads();
  unsigned short* dst = cwp + (size_t)f * NKI;
  for (int i = threadIdx.x; i < NKI; i += 256) {
    int kk = i / NC, cc = i - kk * NC;
    dst[i] = f2bf(s[cc * 9 + kk]);
  }
}

// fp32 -> bf16 with scale (scale folds q's 192^-0.5 into qw)
__global__ __launch_bounds__(256) void k_cvt_scale(const float* __restrict__ x,
    unsigned short* __restrict__ y, int n, float scale) {
  int i = blockIdx.x * 256 + threadIdx.x;
  if (i < n) y[i] = f2bf(x[i] * scale);
}

// Projection GEMM: A[M,K]bf16 @ W[N=384,K]bf16^T. 128x128 tile, m97 structure.
// mode 0: bf16 row write to Cb. mode 1: Cf += acc (fused residual, o-proj).
// mode 2: bf16 transposed write (v-proj -> vtb layout [(b*2+h)*192+d][512]).
__global__ __launch_bounds__(256) void k_pgemm_mfma(
    const unsigned short* __restrict__ A,
    const unsigned short* __restrict__ W,
    unsigned short* __restrict__ Cb,
    float* __restrict__ Cf,
    int K, int mode) {
  __shared__ unsigned short As[128 * 32];
  __shared__ unsigned short Bs[128 * 32];
  const int bn = blockIdx.x * 128;
  const int bm = blockIdx.y * 128;
  const int tid = threadIdx.x;
  const int lane = tid & 63, wv = tid >> 6;
  const int wr = (wv >> 1) * 64, wc = (wv & 1) * 64;
  f32x4 acc[4][4] = {};

  const int chunk = wv * 2;
  const int rloc = chunk * 16 + (lane >> 2);
  const int slot = (lane & 3) * 8;
  const size_t abase = ((size_t)(bm + rloc)) * K + slot;
  const size_t bbase = ((size_t)(bn + rloc)) * K + slot;
  unsigned short* AsW0 = &As[chunk * 512];
  unsigned short* AsW1 = &As[(chunk + 1) * 512];
  unsigned short* BsW0 = &Bs[chunk * 512];
  unsigned short* BsW1 = &Bs[(chunk + 1) * 512];

  const int rsel = lane & 15, ksel = (lane >> 4) * 8;

  for (int kt = 0; kt < K; kt += 32) {
    GLOAD16(A + abase + kt, AsW0);
    GLOAD16(A + abase + kt + (size_t)16 * K, AsW1);
    GLOAD16(W + bbase + kt, BsW0);
    GLOAD16(W + bbase + kt + (size_t)16 * K, BsW1);
    __syncthreads();
    bf16x8 af[4], bfr[4];
#pragma unroll
    for (int m = 0; m < 4; ++m)
      af[m] = *(const bf16x8*)&As[(wr + m * 16 + rsel) * 32 + ksel];
#pragma unroll
    for (int n = 0; n < 4; ++n)
      bfr[n] = *(const bf16x8*)&Bs[(wc + n * 16 + rsel) * 32 + ksel];
#pragma unroll
    for (int m = 0; m < 4; ++m)
#pragma unroll
      for (int n = 0; n < 4; ++n)
        acc[m][n] = __builtin_amdgcn_mfma_f32_16x16x32_bf16(af[m], bfr[n], acc[m][n], 0, 0, 0);
    __syncthreads();
  }

  const int col0 = bn + wc + (lane & 15);
  const int row0 = bm + wr + (lane >> 4) * 4;
#pragma unroll
  for (int m = 0; m < 4; ++m) {
#pragma unroll
    for (int n = 0; n < 4; ++n) {
      int col = col0 + n * 16;
#pragma unroll
      for (int r = 0; r < 4; ++r) {
        int row = row0 + m * 16 + r;
        if (mode == 0) {
          Cb[(size_t)row * NC + col] = f2bf(acc[m][n][r]);
        } else if (mode == 1) {
          size_t oi = (size_t)row * NC + col;
          Cf[oi] = acc[m][n][r] + Cf[oi];
        } else {
          // vtb[(b*384 + col)*512 + j], b = row>>9, j = row&511
          Cb[((size_t)((row >> 9) * 384 + col)) * 512 + (row & 511)] = f2bf(acc[m][n][r]);
        }
      }
    }
  }
}

// Conv1d(C->4C,k=9,SAME) implicit GEMM. 256x256 tile, BK=64, 8 waves (2Mx4N),
// per-wave 128x64 output (43 FLOP/LDS-byte), double-buffered LDS,
// distance-2 prefetch with counted vmcnt (never 0 mid-loop),
// granule-XOR swizzle (pre-swizzled global src + XOR'd ds_read).
// Fused (+cb)*9^-0.5 -> gelu(exact) -> bf16 store.
__global__ __launch_bounds__(512, 2) void k_conv_mfma(
    const unsigned short* __restrict__ Ypad,
    const unsigned short* __restrict__ Wp,
    const float* __restrict__ cb,
    unsigned short* __restrict__ H) {
  __shared__ unsigned short As[2][256 * 64];   // 64 KB
  __shared__ unsigned short Bs[2][256 * 64];   // 64 KB
  // 384 blocks = 8 XCD chunks x 48: keep one Wp panel L2-resident per XCD
  const int id = blockIdx.x;
  const int swz = (id & 7) * 48 + (id >> 3);
  const int bm = (swz % 64) * 256;
  const int bn = (swz / 64) * 256;
  const int b = bm >> 11, t0 = bm & 2047;
  const int tid = threadIdx.x;
  const int lane = tid & 63, wv = tid >> 6;
  const int wvM = wv >> 2, wvN = wv & 3;
  const int rsel = lane & 15, ghi = lane >> 4;
  const int l8 = lane >> 3, g8 = lane & 7;
  const int gsrc = (g8 ^ l8) * 8;              // pre-swizzled source granule (shorts)

  f32x4 acc[8][4] = {};

  const size_t arow0 = (size_t)(b * TPAD + t0 + wv * 32 + l8);   // A stage row (lane)
  const size_t brow0 = (size_t)(bn + wv * 32 + l8);              // B stage row (lane)

#define CONV_STAGE(T, DB)                                                     \
  {                                                                           \
    const int kt_ = (T) * 64;                                                 \
    const int kk_ = kt_ / NC;                                                 \
    const int c0_ = kt_ - kk_ * NC;                                           \
    const size_t asrc_ = (arow0 + kk_) * NC + c0_ + gsrc;                     \
    GLOAD16(Ypad + asrc_, &As[DB][(wv * 32) * 64]);                           \
    GLOAD16(Ypad + asrc_ + (size_t)8 * NC, &As[DB][(wv * 32 + 8) * 64]);      \
    GLOAD16(Ypad + asrc_ + (size_t)16 * NC, &As[DB][(wv * 32 + 16) * 64]);    \
    GLOAD16(Ypad + asrc_ + (size_t)24 * NC, &As[DB][(wv * 32 + 24) * 64]);    \
    const size_t bsrc_ = brow0 * NKI + kt_ + gsrc;                            \
    GLOAD16(Wp + bsrc_, &Bs[DB][(wv * 32) * 64]);                             \
    GLOAD16(Wp + bsrc_ + (size_t)8 * NKI, &Bs[DB][(wv * 32 + 8) * 64]);       \
    GLOAD16(Wp + bsrc_ + (size_t)16 * NKI, &Bs[DB][(wv * 32 + 16) * 64]);     \
    GLOAD16(Wp + bsrc_ + (size_t)24 * NKI, &Bs[DB][(wv * 32 + 24) * 64]);     \
  }

  // prologue: stage tiles 0 and 1
  CONV_STAGE(0, 0);
  CONV_STAGE(1, 1);
  asm volatile("s_waitcnt vmcnt(8)" ::: "memory");
  __builtin_amdgcn_sched_barrier(0);
  __builtin_amdgcn_s_barrier();

  const int arow = wvM * 128;
  const int brow = wvN * 64;
  int db = 0;
  for (int t = 0; t < 54; ++t) {
    bf16x8 a0[8], b0[4];
#pragma unroll
    for (int m = 0; m < 8; ++m) {
      int r = arow + m * 16 + rsel;
      a0[m] = *(const bf16x8*)&As[db][r * 64 + ((ghi ^ (r & 7)) * 8)];
    }
#pragma unroll
    for (int n = 0; n < 4; ++n) {
      int r = brow + n * 16 + rsel;
      b0[n] = *(const bf16x8*)&Bs[db][r * 64 + ((ghi ^ (r & 7)) * 8)];
    }
    __builtin_amdgcn_s_setprio(1);
#pragma unroll
    for (int m = 0; m < 8; ++m)
#pragma unroll
      for (int n = 0; n < 4; ++n)
        acc[m][n] = __builtin_amdgcn_mfma_f32_16x16x32_bf16(a0[m], b0[n], acc[m][n], 0, 0, 0);
    __builtin_amdgcn_s_setprio(0);
    bf16x8 a1[8], b1[4];
#pragma unroll
    for (int m = 0; m < 8; ++m) {
      int r = arow + m * 16 + rsel;
      a1[m] = *(const bf16x8*)&As[db][r * 64 + (((4 + ghi) ^ (r & 7)) * 8)];
    }
#pragma unroll
    for (int n = 0; n < 4; ++n) {
      int r = brow + n * 16 + rsel;
      b1[n] = *(const bf16x8*)&Bs[db][r * 64 + (((4 + ghi) ^ (r & 7)) * 8)];
    }
    asm volatile("s_waitcnt lgkmcnt(0)" ::: "memory");   // all reads of buf[db] done
    __builtin_amdgcn_sched_barrier(0);
    __builtin_amdgcn_s_barrier();                        // ... in every wave
    if (t + 2 < 54) CONV_STAGE(t + 2, db);               // safe: buf[db] free now
    __builtin_amdgcn_s_setprio(1);
#pragma unroll
    for (int m = 0; m < 8; ++m)
#pragma unroll
      for (int n = 0; n < 4; ++n)
        acc[m][n] = __builtin_amdgcn_mfma_f32_16x16x32_bf16(a1[m], b1[n], acc[m][n], 0, 0, 0);
    __builtin_amdgcn_s_setprio(0);
    __builtin_amdgcn_sched_barrier(0);
    if (t + 2 < 54) {
      asm volatile("s_waitcnt vmcnt(8)" ::: "memory");   // tile t+1 landed; t+2 in flight
    } else {
      asm volatile("s_waitcnt vmcnt(0)" ::: "memory");   // epilogue drain
    }
    __builtin_amdgcn_sched_barrier(0);
    __builtin_amdgcn_s_barrier();
    db ^= 1;
  }
#undef CONV_STAGE

  const int col0 = bn + wvN * 64 + rsel;
  const int row0 = bm + wvM * 128 + ghi * 4;
#pragma unroll
  for (int m = 0; m < 8; ++m) {
#pragma unroll
    for (int n = 0; n < 4; ++n) {
      int col = col0 + n * 16;
      float cbv = cb[col];
#pragma unroll
      for (int r = 0; r < 4; ++r) {
        int row = row0 + m * 16 + r;
        float xv = (acc[m][n][r] + cbv) * 0.33333333333333333f;
        float ge = 0.5f * xv * (1.f + erff(xv * 0.70710678118654752f));
        H[(size_t)row * NF + col] = f2bf(ge);
      }
    }
  }
}

// FFN linear: x1a[m][n] += H[m][:]@lw[n][:] + lb[n].  bf16 MFMA, m97 structure.
__global__ __launch_bounds__(256) void k_lin_mfma(
    const unsigned short* __restrict__ H,
    const unsigned short* __restrict__ Wb,
    const float* __restrict__ lb,
    float* __restrict__ x1a) {
  __shared__ unsigned short As[128 * 32];
  __shared__ unsigned short Bs[128 * 32];
  const int bn = blockIdx.x * 128;
  const int bm = blockIdx.y * 128;
  const int tid = threadIdx.x;
  const int lane = tid & 63, wv = tid >> 6;
  const int wr = (wv >> 1) * 64, wc = (wv & 1) * 64;
  f32x4 acc[4][4] = {};

  const int chunk = wv * 2;
  const int rloc = chunk * 16 + (lane >> 2);
  const int slot = (lane & 3) * 8;
  const size_t abase = ((size_t)(bm + rloc)) * NF + slot;
  const size_t bbase = ((size_t)(bn + rloc)) * NF + slot;
  unsigned short* AsW0 = &As[chunk * 512];
  unsigned short* AsW1 = &As[(chunk + 1) * 512];
  unsigned short* BsW0 = &Bs[chunk * 512];
  unsigned short* BsW1 = &Bs[(chunk + 1) * 512];

  const int rsel = lane & 15, ksel = (lane >> 4) * 8;

  for (int kt = 0; kt < NF; kt += 32) {
    GLOAD16(H + abase + kt, AsW0);
    GLOAD16(H + abase + kt + (size_t)16 * NF, AsW1);
    GLOAD16(Wb + bbase + kt, BsW0);
    GLOAD16(Wb + bbase + kt + (size_t)16 * NF, BsW1);
    __syncthreads();
    bf16x8 af[4], bfr[4];
#pragma unroll
    for (int m = 0; m < 4; ++m)
      af[m] = *(const bf16x8*)&As[(wr + m * 16 + rsel) * 32 + ksel];
#pragma unroll
    for (int n = 0; n < 4; ++n)
      bfr[n] = *(const bf16x8*)&Bs[(wc + n * 16 + rsel) * 32 + ksel];
#pragma unroll
    for (int m = 0; m < 4; ++m)
#pragma unroll
      for (int n = 0; n < 4; ++n)
        acc[m][n] = __builtin_amdgcn_mfma_f32_16x16x32_bf16(af[m], bfr[n], acc[m][n], 0, 0, 0);
    __syncthreads();
  }

  const int col0 = bn + wc + (lane & 15);
  const int row0 = bm + wr + (lane >> 4) * 4;
#pragma unroll
  for (int m = 0; m < 4; ++m) {
#pragma unroll
    for (int n = 0; n < 4; ++n) {
      int col = col0 + n * 16;
      float lbv = lb[col];
#pragma unroll
      for (int r = 0; r < 4; ++r) {
        int row = row0 + m * 16 + r;
        size_t oi = (size_t)row * NC + col;
        x1a[oi] = acc[m][n][r] + lbv + x1a[oi];
      }
    }
  }
}

// Windowed cross-attention, MFMA flash-style. bf16 output (feeds o-projection).
__global__ __launch_bounds__(256) void k_attn_mfma(
    const unsigned short* __restrict__ qbb,   // [8*2048][384] bf16 (q*scaling folded in W)
    const unsigned short* __restrict__ kbb,   // [8*512][384] bf16
    const unsigned short* __restrict__ vtb,   // [(b*2+h)*192+d][512] bf16
    unsigned short* __restrict__ o, int guided, float* __restrict__ gl) {
  __shared__ unsigned short lds[32768];
  const int tid = threadIdx.x;
  const int lane = tid & 63, wv = tid >> 6;
  const int rsel = lane & 15, ghi = lane >> 4;
  const int idx = blockIdx.x;
  const int tg = idx & 31;
  const int bh = idx >> 5;
  const int h = bh & 1, b = bh >> 1;
  const int t0 = tg * 64;
  const int c0 = t0 >> 2;
  int klo = c0 - 51; if (klo < 0) klo = 0;
  klo &= ~7;                       // 16B-align for global_load_lds on vtb
  if (klo > 384) klo = 384;        // keep window inside [0,512)

  // Q fragments: A-operand layout, row = lane&15, k = ghi*8 (+32 per step)
  const unsigned short* qrow = qbb + (size_t)(b * NT1 + t0 + wv * 16 + rsel) * NC + h * ND;
  bf16x8 qf[6];
#pragma unroll
  for (int kk = 0; kk < 6; ++kk)
    qf[kk] = *(const bf16x8*)(qrow + kk * 32 + ghi * 8);

  // stage K window [128 keys][192] bf16, source pre-swizzled (granule ^ row&7)
  {
    const size_t kbase = (size_t)(b * NT2 + klo) * NC + h * ND;
#pragma unroll
    for (int it = 0; it < 12; ++it) {
      int g = it * 256 + tid;
      int row = g / 24, go = g % 24;
      int gs = go ^ (row & 7);
      GLOAD16(kbb + kbase + (size_t)row * NC + gs * 8, &lds[(it * 256 + wv * 64) * 8]);
    }
  }
  __syncthreads();

  // QK^T: 16 queries x 128 keys per wave
  f32x4 accs[8] = {};
#pragma unroll
  for (int kk = 0; kk < 6; ++kk) {
#pragma unroll
    for (int n = 0; n < 8; ++n) {
      int row = n * 16 + rsel;
      bf16x8 bfr = *(const bf16x8*)&lds[row * 192 + (((kk * 4 + ghi) ^ (rsel & 7)) * 8)];
      accs[n] = __builtin_amdgcn_mfma_f32_16x16x32_bf16(qf[kk], bfr, accs[n], 0, 0, 0);
    }
  }

  // masked softmax per query row; rows live on 16-lane groups (row=ghi*4+r, col=rsel)
  unsigned short* pl = &lds[24576 + wv * 2048];
  float gacc = 0.f;
  const int t0w = t0 + wv * 16;
#pragma unroll
  for (int r = 0; r < 4; ++r) {
    int t = t0w + ghi * 4 + r;
    int c = t >> 2;
    int loq = c - 51; if (loq < 0) loq = 0;
    int hiq = c + 51; if (hiq > NT2) hiq = NT2;
    float sv[8];
    float mx = -1e30f;
#pragma unroll
    for (int n = 0; n < 8; ++n) {
      int j = klo + n * 16 + rsel;
      float s = (j >= loq && j < hiq) ? accs[n][r] : -1e30f;
      sv[n] = s; mx = fmaxf(mx, s);
    }
#pragma unroll
    for (int off = 1; off < 16; off <<= 1) mx = fmaxf(mx, __shfl_xor(mx, off));
    float e[8]; float se = 0.f;
#pragma unroll
    for (int n = 0; n < 8; ++n) { e[n] = __expf(sv[n] - mx); se += e[n]; }
#pragma unroll
    for (int off = 1; off < 16; off <<= 1) se += __shfl_xor(se, off);
    float inv = 1.f / se;
    int q = ghi * 4 + r;
#pragma unroll
    for (int n = 0; n < 8; ++n) {
      float pv = e[n] * inv;
      int klocal = n * 16 + rsel;
      pl[q * 128 + (((klocal >> 3) ^ (q & 7)) * 8) + (klocal & 7)] = f2bf(pv);
      if (guided) {
        int j = klo + klocal;
        float d = (float)j * (1.f / NT2) - (float)t * (1.f / NT1);
        gacc += pv * (1.f - __expf(-(d * d) * 5.5555555556f));
      }
    }
  }
  if (guided) {
    gacc = warp_sum(gacc);
    if (lane == 0) atomicAdd(gl, gacc * (1.f / 16777216.f));
  }
  __syncthreads();

  // stage VT window [192 chans][128 keys] bf16 into the K buffer (reuse)
  {
    const size_t vbase = ((size_t)(b * 2 + h) * ND) * NT2 + klo;
#pragma unroll
    for (int it = 0; it < 12; ++it) {
      int g = it * 256 + tid;
      int row = g >> 4, go = g & 15;
      int gs = go ^ (row & 7);
      GLOAD16(vtb + vbase + (size_t)row * NT2 + gs * 8, &lds[(it * 256 + wv * 64) * 8]);
    }
  }
  __syncthreads();

  // PV: P[16x128] @ V[128x192] -> O[16x192]
  f32x4 acco[12] = {};
#pragma unroll
  for (int kt = 0; kt < 4; ++kt) {
    bf16x8 pa = *(const bf16x8*)&pl[rsel * 128 + (((kt * 4 + ghi) ^ (rsel & 7)) * 8)];
#pragma unroll
    for (int n = 0; n < 12; ++n) {
      int row = n * 16 + rsel;
      bf16x8 bfr = *(const bf16x8*)&lds[row * 128 + (((kt * 4 + ghi) ^ (rsel & 7)) * 8)];
      acco[n] = __builtin_amdgcn_mfma_f32_16x16x32_bf16(pa, bfr, acco[n], 0, 0, 0);
    }
  }

  unsigned short* obase = o + (size_t)(b * NT1 + t0w + ghi * 4) * NC + h * ND;
#pragma unroll
  for (int n = 0; n < 12; ++n) {
#pragma unroll
    for (int r = 0; r < 4; ++r) {
      obase[(size_t)r * NC + n * 16 + rsel] = f2bf(acco[n][r]);
    }
  }
}

extern "C" void kernel_launch(void* const* d_in, const int* in_sizes, int n_in,
                              void* d_out, int out_size, void* d_ws, size_t ws_size,
                              hipStream_t stream) {
  (void)in_sizes; (void)n_in; (void)out_size; (void)ws_size;
  const float* x1    = (const float*)d_in[0];
  const float* x2    = (const float*)d_in[1];
  const float* alpha = (const float*)d_in[2];
  const float* ln1_g = (const float*)d_in[3];
  const float* ln1_b = (const float*)d_in[4];
  const float* qw    = (const float*)d_in[5];
  const float* kw    = (const float*)d_in[6];
  const float* vw    = (const float*)d_in[7];
  const float* ow    = (const float*)d_in[8];
  const float* ln2_g = (const float*)d_in[9];
  const float* ln2_b = (const float*)d_in[10];
  const float* cw    = (const float*)d_in[11];
  const float* cb    = (const float*)d_in[12];
  const float* lw    = (const float*)d_in[13];
  const float* lb    = (const float*)d_in[14];
  const float* lnf_g = (const float*)d_in[15];
  const float* lnf_b = (const float*)d_in[16];
  float* out = (float*)d_out;
  float* gl = out + 6291456;   // guided-loss scalar slot

  float* p = (float*)d_ws;
  float* x1a = p; p += 6291456;    // x1 state [16384,384] f32
  // bf16 region (16B-aligned)
  unsigned short* us = (unsigned short*)p;
  unsigned short* x2b  = us; us += 1572864;            // x2+pos bf16 [4096][384]
  unsigned short* tmpb = us; us += 6291456;            // LN1 out / attn out bf16
  unsigned short* ypad = us; us += 8 * TPAD * NC;      // 6316032
  unsigned short* cwpb = us; us += 2 * (size_t)NF * NKI;   // 10616832 (both layers)
  unsigned short* lwb  = us; us += 2 * (size_t)NC * NF;    // 1179648 (both layers)
  unsigned short* hb   = us; us += (size_t)16384 * NF; // 25165824
  unsigned short* qbb  = us; us += 6291456;            // q bf16 [16384][384]
  unsigned short* kbb  = us; us += 1572864;            // k bf16 [4096][384]
  unsigned short* vtb  = us; us += 1572864;            // v^T bf16 [32*192][512]
  unsigned short* qwb  = us; us += 294912;             // weights bf16 (2 layers each)
  unsigned short* kwb  = us; us += 294912;
  unsigned short* vwb  = us; us += 294912;
  unsigned short* owb  = us; us += 294912;

  hipMemsetAsync(gl, 0, sizeof(float), stream);  // atomic accumulator, re-zeroed every launch
  k_zero_guard<<<96, 256, 0, stream>>>(ypad);
  k_add_pos2<<<12288, 256, 0, stream>>>(x1, alpha, x1a, NT1, 3145728);
  k_add_pos2_bf16<<<3072, 256, 0, stream>>>(x2, alpha, x2b, NT2, 786432);

  const float scaling = 0.07216878364870323f;   // 192^-0.5
  // weight conversions, both layers, hoisted
  k_cvt_scale<<<1152, 256, 0, stream>>>(qw, qwb, 294912, scaling);
  k_cvt_scale<<<1152, 256, 0, stream>>>(kw, kwb, 294912, 1.f);
  k_cvt_scale<<<1152, 256, 0, stream>>>(vw, vwb, 294912, 1.f);
  k_cvt_scale<<<1152, 256, 0, stream>>>(ow, owb, 294912, 1.f);
  k_cvt_scale<<<4608, 256, 0, stream>>>(lw, lwb, 1179648, 1.f);
  k_pack_cw2<<<3072, 256, 0, stream>>>(cw, cwpb);

  for (int l = 0; l < 2; ++l) {
    k_ln_bf16<<<4096, 256, 0, stream>>>(x1a, ln1_g + l * 384, ln1_b + l * 384, tmpb);
    k_pgemm_mfma<<<dim3(3, 128), 256, 0, stream>>>(tmpb, qwb + (size_t)l * 147456, qbb, nullptr, 384, 0);
    k_pgemm_mfma<<<dim3(3, 32), 256, 0, stream>>>(x2b, kwb + (size_t)l * 147456, kbb, nullptr, 384, 0);
    k_pgemm_mfma<<<dim3(3, 32), 256, 0, stream>>>(x2b, vwb + (size_t)l * 147456, vtb, nullptr, 384, 2);
    k_attn_mfma<<<512, 256, 0, stream>>>(qbb, kbb, vtb, tmpb, l == 0 ? 1 : 0, gl);
    k_pgemm_mfma<<<dim3(3, 128), 256, 0, stream>>>(tmpb, owb + (size_t)l * 147456, nullptr, x1a, 384, 1);
    // FFN: ln2 -> bf16 padded, conv implicit GEMM (deep-pipelined MFMA), linear (MFMA)
    k_ln_bf16p<<<4096, 256, 0, stream>>>(x1a, ln2_g + l * 384, ln2_b + l * 384, ypad);
    k_conv_mfma<<<384, 512, 0, stream>>>(ypad, cwpb + (size_t)l * 5308416, cb + l * 1536, hb);
    k_lin_mfma<<<dim3(3, 128), 256, 0, stream>>>(hb, lwb + (size_t)l * 589824, lb + l * 384, x1a);
  }
  k_ln<<<4096, 256, 0, stream>>>(x1a, lnf_g, lnf_b, out, 16384);
}

// Round 5
// 780.842 us; speedup vs baseline: 1.0151x; 1.0151x over previous
//
#include <hip/hip_runtime.h>
#include <math.h>

#define NB 8
#define NT1 2048
#define NT2 512
#define NC 384
#define ND 192
#define NF 1536
#define NKI 3456   // 9*384 implicit-GEMM K for conv
#define TPAD 2056  // 2048 + 4 guard rows top and bottom

typedef __attribute__((ext_vector_type(8))) short bf16x8;
typedef __attribute__((ext_vector_type(4))) float f32x4;

#define GLOAD16(gsrc, ldst) \
  __builtin_amdgcn_global_load_lds((const __attribute__((address_space(1))) void*)(gsrc), \
                                   (__attribute__((address_space(3))) void*)(ldst), 16, 0, 0)

static __device__ __forceinline__ unsigned short f2bf(float f) {
  unsigned int u = __float_as_uint(f);
  unsigned int r = (u + 0x7fffu + ((u >> 16) & 1u)) >> 16;
  return (unsigned short)r;
}

static __device__ __forceinline__ float warp_sum(float v) {
#pragma unroll
  for (int off = 32; off > 0; off >>= 1) v += __shfl_xor(v, off);
  return v;
}

// x += alpha * sin-pos; thread handles (t,j) pair: sin at c=j, cos at c=j+192
__global__ __launch_bounds__(256) void k_add_pos2(const float* __restrict__ x,
    const float* __restrict__ alpha_p, float* __restrict__ y, int T, int total2) {
  int i = blockIdx.x * 256 + threadIdx.x;
  if (i >= total2) return;
  int j = i % 192;
  int row = i / 192;
  int t = row % T;
  float freq = __expf(-0.0482216773f * (float)j);   // ln(10000)/191
  float ang = (float)(t + 1) * freq;
  float sn, cs;
  __sincosf(ang, &sn, &cs);
  float a = alpha_p[0];
  size_t base = (size_t)row * NC;
  y[base + j] = x[base + j] + a * sn;
  y[base + j + 192] = x[base + j + 192] + a * cs;
}

__global__ __launch_bounds__(256) void k_add_pos2_bf16(const float* __restrict__ x,
    const float* __restrict__ alpha_p, unsigned short* __restrict__ y, int T, int total2) {
  int i = blockIdx.x * 256 + threadIdx.x;
  if (i >= total2) return;
  int j = i % 192;
  int row = i / 192;
  int t = row % T;
  float freq = __expf(-0.0482216773f * (float)j);
  float ang = (float)(t + 1) * freq;
  float sn, cs;
  __sincosf(ang, &sn, &cs);
  float a = alpha_p[0];
  size_t base = (size_t)row * NC;
  y[base + j] = f2bf(x[base + j] + a * sn);
  y[base + j + 192] = f2bf(x[base + j + 192] + a * cs);
}

// LayerNorm over last dim (384). One wave per row. fp32 out (final LN).
__global__ __launch_bounds__(256) void k_ln(const float* __restrict__ x,
    const float* __restrict__ g, const float* __restrict__ b,
    float* __restrict__ y, int nrows) {
  int row = blockIdx.x * 4 + (threadIdx.x >> 6);
  int lane = threadIdx.x & 63;
  if (row >= nrows) return;
  const float* xr = x + (size_t)row * NC;
  float v[6];
  float s = 0.f, s2 = 0.f;
#pragma unroll
  for (int i = 0; i < 6; ++i) {
    float t = xr[lane + 64 * i];
    v[i] = t; s += t; s2 += t * t;
  }
  s = warp_sum(s); s2 = warp_sum(s2);
  float mean = s * (1.f / NC);
  float var = s2 * (1.f / NC) - mean * mean;
  float rs = rsqrtf(var + 1e-5f);
  float* yr = y + (size_t)row * NC;
#pragma unroll
  for (int i = 0; i < 6; ++i) {
    int cc = lane + 64 * i;
    yr[cc] = (v[i] - mean) * rs * g[cc] + b[cc];
  }
}

// LayerNorm -> bf16 (unpadded), feeds MFMA projections
__global__ __launch_bounds__(256) void k_ln_bf16(const float* __restrict__ x,
    const float* __restrict__ g, const float* __restrict__ b,
    unsigned short* __restrict__ y) {
  int row = blockIdx.x * 4 + (threadIdx.x >> 6);
  int lane = threadIdx.x & 63;
  const float* xr = x + (size_t)row * NC;
  float v[6];
  float s = 0.f, s2 = 0.f;
#pragma unroll
  for (int i = 0; i < 6; ++i) {
    float t = xr[lane + 64 * i];
    v[i] = t; s += t; s2 += t * t;
  }
  s = warp_sum(s); s2 = warp_sum(s2);
  float mean = s * (1.f / NC);
  float var = s2 * (1.f / NC) - mean * mean;
  float rs = rsqrtf(var + 1e-5f);
  unsigned short* yr = y + (size_t)row * NC;
#pragma unroll
  for (int i = 0; i < 6; ++i) {
    int cc = lane + 64 * i;
    yr[cc] = f2bf((v[i] - mean) * rs * g[cc] + b[cc]);
  }
}

// LayerNorm -> bf16 into guard-padded [8][2056][384] buffer (row t -> t+4)
__global__ __launch_bounds__(256) void k_ln_bf16p(const float* __restrict__ x,
    const float* __restrict__ g, const float* __restrict__ b,
    unsigned short* __restrict__ ypad) {
  int row = blockIdx.x * 4 + (threadIdx.x >> 6);
  int lane = threadIdx.x & 63;
  const float* xr = x + (size_t)row * NC;
  float v[6];
  float s = 0.f, s2 = 0.f;
#pragma unroll
  for (int i = 0; i < 6; ++i) {
    float t = xr[lane + 64 * i];
    v[i] = t; s += t; s2 += t * t;
  }
  s = warp_sum(s); s2 = warp_sum(s2);
  float mean = s * (1.f / NC);
  float var = s2 * (1.f / NC) - mean * mean;
  float rs = rsqrtf(var + 1e-5f);
  int bb = row >> 11, t = row & 2047;
  unsigned short* yr = ypad + ((size_t)(bb * TPAD + t + 4)) * NC;
#pragma unroll
  for (int i = 0; i < 6; ++i) {
    int cc = lane + 64 * i;
    yr[cc] = f2bf((v[i] - mean) * rs * g[cc] + b[cc]);
  }
}

// zero the 4 guard rows top+bottom of each batch slab in ypad
__global__ __launch_bounds__(256) void k_zero_guard(unsigned short* __restrict__ ypad) {
  int i = blockIdx.x * 256 + threadIdx.x;   // 8*8*384 = 24576
  if (i >= 24576) return;
  int c = i % NC;
  int r = (i / NC) % 8;
  int b = i / (NC * 8);
  int t = (r < 4) ? r : (2048 + r);         // rows 0..3 and 2052..2055
  ypad[((size_t)b * TPAD + t) * NC + c] = 0;
}

// pack + convert cw[f][c][kk] -> cwp[f][kk*384+c] bf16. One block per f-row,
// coalesced load -> LDS -> coalesced store (LDS read stride 9: conflict-free).
__global__ __launch_bounds__(256) void k_pack_cw2(const float* __restrict__ cw,
    unsigned short* __restrict__ cwp) {
  __shared__ float s[NKI];
  int f = blockIdx.x;
  const float* src = cw + (size_t)f * NKI;
  for (int i = threadIdx.x; i < NKI; i += 256) s[i] = src[i];
  __syncthreads();
  unsigned short* dst = cwp + (size_t)f * NKI;
  for (int i = threadIdx.x; i < NKI; i += 256) {
    int kk = i / NC, cc = i - kk * NC;
    dst[i] = f2bf(s[cc * 9 + kk]);
  }
}

// fp32 -> bf16 with scale (scale folds q's 192^-0.5 into qw)
__global__ __launch_bounds__(256) void k_cvt_scale(const float* __restrict__ x,
    unsigned short* __restrict__ y, int n, float scale) {
  int i = blockIdx.x * 256 + threadIdx.x;
  if (i < n) y[i] = f2bf(x[i] * scale);
}

// Projection GEMM: A[M,K]bf16 @ W[N=384,K]bf16^T. 128x128 tile, m97 structure.
// mode 0: bf16 row write to Cb. mode 1: Cf += acc (fused residual, o-proj).
// mode 2: bf16 transposed write (v-proj -> vtb layout [(b*2+h)*192+d][512]).
__global__ __launch_bounds__(256) void k_pgemm_mfma(
    const unsigned short* __restrict__ A,
    const unsigned short* __restrict__ W,
    unsigned short* __restrict__ Cb,
    float* __restrict__ Cf,
    int K, int mode) {
  __shared__ unsigned short As[128 * 32];
  __shared__ unsigned short Bs[128 * 32];
  const int bn = blockIdx.x * 128;
  const int bm = blockIdx.y * 128;
  const int tid = threadIdx.x;
  const int lane = tid & 63, wv = tid >> 6;
  const int wr = (wv >> 1) * 64, wc = (wv & 1) * 64;
  f32x4 acc[4][4] = {};

  const int chunk = wv * 2;
  const int rloc = chunk * 16 + (lane >> 2);
  const int slot = (lane & 3) * 8;
  const size_t abase = ((size_t)(bm + rloc)) * K + slot;
  const size_t bbase = ((size_t)(bn + rloc)) * K + slot;
  unsigned short* AsW0 = &As[chunk * 512];
  unsigned short* AsW1 = &As[(chunk + 1) * 512];
  unsigned short* BsW0 = &Bs[chunk * 512];
  unsigned short* BsW1 = &Bs[(chunk + 1) * 512];

  const int rsel = lane & 15, ksel = (lane >> 4) * 8;

  for (int kt = 0; kt < K; kt += 32) {
    GLOAD16(A + abase + kt, AsW0);
    GLOAD16(A + abase + kt + (size_t)16 * K, AsW1);
    GLOAD16(W + bbase + kt, BsW0);
    GLOAD16(W + bbase + kt + (size_t)16 * K, BsW1);
    __syncthreads();
    bf16x8 af[4], bfr[4];
#pragma unroll
    for (int m = 0; m < 4; ++m)
      af[m] = *(const bf16x8*)&As[(wr + m * 16 + rsel) * 32 + ksel];
#pragma unroll
    for (int n = 0; n < 4; ++n)
      bfr[n] = *(const bf16x8*)&Bs[(wc + n * 16 + rsel) * 32 + ksel];
#pragma unroll
    for (int m = 0; m < 4; ++m)
#pragma unroll
      for (int n = 0; n < 4; ++n)
        acc[m][n] = __builtin_amdgcn_mfma_f32_16x16x32_bf16(af[m], bfr[n], acc[m][n], 0, 0, 0);
    __syncthreads();
  }

  const int col0 = bn + wc + (lane & 15);
  const int row0 = bm + wr + (lane >> 4) * 4;
#pragma unroll
  for (int m = 0; m < 4; ++m) {
#pragma unroll
    for (int n = 0; n < 4; ++n) {
      int col = col0 + n * 16;
#pragma unroll
      for (int r = 0; r < 4; ++r) {
        int row = row0 + m * 16 + r;
        if (mode == 0) {
          Cb[(size_t)row * NC + col] = f2bf(acc[m][n][r]);
        } else if (mode == 1) {
          size_t oi = (size_t)row * NC + col;
          Cf[oi] = acc[m][n][r] + Cf[oi];
        } else {
          // vtb[(b*384 + col)*512 + j], b = row>>9, j = row&511
          Cb[((size_t)((row >> 9) * 384 + col)) * 512 + (row & 511)] = f2bf(acc[m][n][r]);
        }
      }
    }
  }
}

// Conv1d(C->4C,k=9,SAME) implicit GEMM. 256x128 tile, BK=32, 8 waves (4Mx2N,
// per-wave 64x64), double-buffered LDS (48 KB -> 2 blocks/CU), distance-2
// prefetch with counted vmcnt(3) (3 loads/thread/tile), granule-XOR swizzle
// over 4-granule rows (uniform 2-way bank aliasing = free).
// Fused (+cb)*9^-0.5 -> gelu(exact) -> bf16 store.
__global__ __launch_bounds__(512, 4) void k_conv_mfma(
    const unsigned short* __restrict__ Ypad,
    const unsigned short* __restrict__ Wp,
    const float* __restrict__ cb,
    unsigned short* __restrict__ H) {
  __shared__ unsigned short As[2][256 * 32];   // 32 KB
  __shared__ unsigned short Bs[2][128 * 32];   // 16 KB
  const int bm = blockIdx.x * 256;             // natural order: XCD = bm%8 affinity
  const int bn = blockIdx.y * 128;
  const int b = bm >> 11, t0 = bm & 2047;
  const int tid = threadIdx.x;
  const int lane = tid & 63, wv = tid >> 6;
  const int wvM = wv >> 1, wvN = wv & 1;
  const int rsel = lane & 15, ghi = lane >> 4;
  const int lr4 = lane >> 2, lg = lane & 3;    // stage: row-within-16, granule slot

  f32x4 acc[4][4] = {};

  // stage lane-constant bases (content at dest slot g is source granule g^xr)
  const int arloc0 = wv * 32 + lr4;            // A local rows: instr0, instr1 = +16
  const int brloc  = wv * 16 + lr4;            // B local row
  const int axr0 = (arloc0 >> 1) & 3;
  const int axr1 = ((arloc0 + 16) >> 1) & 3;
  const int bxr  = (brloc >> 1) & 3;
  const size_t abase0 = ((size_t)(b * TPAD + t0 + arloc0)) * NC + ((lg ^ axr0) * 8);
  const size_t abase1 = ((size_t)(b * TPAD + t0 + arloc0 + 16)) * NC + ((lg ^ axr1) * 8);
  const size_t bbase  = ((size_t)(bn + brloc)) * NKI + ((lg ^ bxr) * 8);

#define CONV_STAGE(T, DB)                                                  \
  {                                                                        \
    const int kt_ = (T) * 32;                                              \
    const int kk_ = kt_ / NC;                                              \
    const int c0_ = kt_ - kk_ * NC;                                        \
    const size_t ao_ = (size_t)kk_ * NC + c0_;                             \
    GLOAD16(Ypad + abase0 + ao_, &As[DB][(wv * 32) * 32]);                 \
    GLOAD16(Ypad + abase1 + ao_, &As[DB][(wv * 32 + 16) * 32]);            \
    GLOAD16(Wp + bbase + kt_, &Bs[DB][(wv * 16) * 32]);                    \
  }

  // prologue: stage tiles 0 and 1; wait own tile-0 loads (3 of 6), barrier joins all
  CONV_STAGE(0, 0);
  CONV_STAGE(1, 1);
  asm volatile("s_waitcnt vmcnt(3)" ::: "memory");
  __builtin_amdgcn_sched_barrier(0);
  __builtin_amdgcn_s_barrier();

  const int arow = wvM * 64;
  const int brow = wvN * 64;
  int db = 0;
  for (int t = 0; t < 108; ++t) {
    bf16x8 af[4], bfr[4];
#pragma unroll
    for (int m = 0; m < 4; ++m) {
      int r = arow + m * 16 + rsel;
      af[m] = *(const bf16x8*)&As[db][r * 32 + ((ghi ^ ((r >> 1) & 3)) * 8)];
    }
#pragma unroll
    for (int n = 0; n < 4; ++n) {
      int r = brow + n * 16 + rsel;
      bfr[n] = *(const bf16x8*)&Bs[db][r * 32 + ((ghi ^ ((r >> 1) & 3)) * 8)];
    }
    asm volatile("s_waitcnt lgkmcnt(0)" ::: "memory");   // frags in regs
    __builtin_amdgcn_sched_barrier(0);
    __builtin_amdgcn_s_barrier();                        // all waves done with buf[db]
    if (t + 2 < 108) CONV_STAGE(t + 2, db);              // overwrite freed buffer
    __builtin_amdgcn_s_setprio(1);
#pragma unroll
    for (int m = 0; m < 4; ++m)
#pragma unroll
      for (int n = 0; n < 4; ++n)
        acc[m][n] = __builtin_amdgcn_mfma_f32_16x16x32_bf16(af[m], bfr[n], acc[m][n], 0, 0, 0);
    __builtin_amdgcn_s_setprio(0);
    __builtin_amdgcn_sched_barrier(0);
    if (t + 2 < 108) {
      asm volatile("s_waitcnt vmcnt(3)" ::: "memory");   // own t+1 landed; t+2 flying
    } else {
      asm volatile("s_waitcnt vmcnt(0)" ::: "memory");   // epilogue drain
    }
    __builtin_amdgcn_sched_barrier(0);
    __builtin_amdgcn_s_barrier();                        // joins: all t+1 resident
    db ^= 1;
  }
#undef CONV_STAGE

  const int col0 = bn + wvN * 64 + rsel;
  const int row0 = bm + wvM * 64 + ghi * 4;
#pragma unroll
  for (int m = 0; m < 4; ++m) {
#pragma unroll
    for (int n = 0; n < 4; ++n) {
      int col = col0 + n * 16;
      float cbv = cb[col];
#pragma unroll
      for (int r = 0; r < 4; ++r) {
        int row = row0 + m * 16 + r;
        float xv = (acc[m][n][r] + cbv) * 0.33333333333333333f;
        float ge = 0.5f * xv * (1.f + erff(xv * 0.70710678118654752f));
        H[(size_t)row * NF + col] = f2bf(ge);
      }
    }
  }
}

// FFN linear: x1a[m][n] += H[m][:]@lw[n][:] + lb[n].  bf16 MFMA, m97 structure.
__global__ __launch_bounds__(256) void k_lin_mfma(
    const unsigned short* __restrict__ H,
    const unsigned short* __restrict__ Wb,
    const float* __restrict__ lb,
    float* __restrict__ x1a) {
  __shared__ unsigned short As[128 * 32];
  __shared__ unsigned short Bs[128 * 32];
  const int bn = blockIdx.x * 128;
  const int bm = blockIdx.y * 128;
  const int tid = threadIdx.x;
  const int lane = tid & 63, wv = tid >> 6;
  const int wr = (wv >> 1) * 64, wc = (wv & 1) * 64;
  f32x4 acc[4][4] = {};

  const int chunk = wv * 2;
  const int rloc = chunk * 16 + (lane >> 2);
  const int slot = (lane & 3) * 8;
  const size_t abase = ((size_t)(bm + rloc)) * NF + slot;
  const size_t bbase = ((size_t)(bn + rloc)) * NF + slot;
  unsigned short* AsW0 = &As[chunk * 512];
  unsigned short* AsW1 = &As[(chunk + 1) * 512];
  unsigned short* BsW0 = &Bs[chunk * 512];
  unsigned short* BsW1 = &Bs[(chunk + 1) * 512];

  const int rsel = lane & 15, ksel = (lane >> 4) * 8;

  for (int kt = 0; kt < NF; kt += 32) {
    GLOAD16(H + abase + kt, AsW0);
    GLOAD16(H + abase + kt + (size_t)16 * NF, AsW1);
    GLOAD16(Wb + bbase + kt, BsW0);
    GLOAD16(Wb + bbase + kt + (size_t)16 * NF, BsW1);
    __syncthreads();
    bf16x8 af[4], bfr[4];
#pragma unroll
    for (int m = 0; m < 4; ++m)
      af[m] = *(const bf16x8*)&As[(wr + m * 16 + rsel) * 32 + ksel];
#pragma unroll
    for (int n = 0; n < 4; ++n)
      bfr[n] = *(const bf16x8*)&Bs[(wc + n * 16 + rsel) * 32 + ksel];
#pragma unroll
    for (int m = 0; m < 4; ++m)
#pragma unroll
      for (int n = 0; n < 4; ++n)
        acc[m][n] = __builtin_amdgcn_mfma_f32_16x16x32_bf16(af[m], bfr[n], acc[m][n], 0, 0, 0);
    __syncthreads();
  }

  const int col0 = bn + wc + (lane & 15);
  const int row0 = bm + wr + (lane >> 4) * 4;
#pragma unroll
  for (int m = 0; m < 4; ++m) {
#pragma unroll
    for (int n = 0; n < 4; ++n) {
      int col = col0 + n * 16;
      float lbv = lb[col];
#pragma unroll
      for (int r = 0; r < 4; ++r) {
        int row = row0 + m * 16 + r;
        size_t oi = (size_t)row * NC + col;
        x1a[oi] = acc[m][n][r] + lbv + x1a[oi];
      }
    }
  }
}

// Windowed cross-attention, MFMA flash-style. bf16 output (feeds o-projection).
__global__ __launch_bounds__(256) void k_attn_mfma(
    const unsigned short* __restrict__ qbb,   // [8*2048][384] bf16 (q*scaling folded in W)
    const unsigned short* __restrict__ kbb,   // [8*512][384] bf16
    const unsigned short* __restrict__ vtb,   // [(b*2+h)*192+d][512] bf16
    unsigned short* __restrict__ o, int guided, float* __restrict__ gl) {
  __shared__ unsigned short lds[32768];
  const int tid = threadIdx.x;
  const int lane = tid & 63, wv = tid >> 6;
  const int rsel = lane & 15, ghi = lane >> 4;
  const int idx = blockIdx.x;
  const int tg = idx & 31;
  const int bh = idx >> 5;
  const int h = bh & 1, b = bh >> 1;
  const int t0 = tg * 64;
  const int c0 = t0 >> 2;
  int klo = c0 - 51; if (klo < 0) klo = 0;
  klo &= ~7;                       // 16B-align for global_load_lds on vtb
  if (klo > 384) klo = 384;        // keep window inside [0,512)

  // Q fragments: A-operand layout, row = lane&15, k = ghi*8 (+32 per step)
  const unsigned short* qrow = qbb + (size_t)(b * NT1 + t0 + wv * 16 + rsel) * NC + h * ND;
  bf16x8 qf[6];
#pragma unroll
  for (int kk = 0; kk < 6; ++kk)
    qf[kk] = *(const bf16x8*)(qrow + kk * 32 + ghi * 8);

  // stage K window [128 keys][192] bf16, source pre-swizzled (granule ^ row&7)
  {
    const size_t kbase = (size_t)(b * NT2 + klo) * NC + h * ND;
#pragma unroll
    for (int it = 0; it < 12; ++it) {
      int g = it * 256 + tid;
      int row = g / 24, go = g % 24;
      int gs = go ^ (row & 7);
      GLOAD16(kbb + kbase + (size_t)row * NC + gs * 8, &lds[(it * 256 + wv * 64) * 8]);
    }
  }
  __syncthreads();

  // QK^T: 16 queries x 128 keys per wave
  f32x4 accs[8] = {};
#pragma unroll
  for (int kk = 0; kk < 6; ++kk) {
#pragma unroll
    for (int n = 0; n < 8; ++n) {
      int row = n * 16 + rsel;
      bf16x8 bfr = *(const bf16x8*)&lds[row * 192 + (((kk * 4 + ghi) ^ (rsel & 7)) * 8)];
      accs[n] = __builtin_amdgcn_mfma_f32_16x16x32_bf16(qf[kk], bfr, accs[n], 0, 0, 0);
    }
  }

  // masked softmax per query row; rows live on 16-lane groups (row=ghi*4+r, col=rsel)
  unsigned short* pl = &lds[24576 + wv * 2048];
  float gacc = 0.f;
  const int t0w = t0 + wv * 16;
#pragma unroll
  for (int r = 0; r < 4; ++r) {
    int t = t0w + ghi * 4 + r;
    int c = t >> 2;
    int loq = c - 51; if (loq < 0) loq = 0;
    int hiq = c + 51; if (hiq > NT2) hiq = NT2;
    float sv[8];
    float mx = -1e30f;
#pragma unroll
    for (int n = 0; n < 8; ++n) {
      int j = klo + n * 16 + rsel;
      float s = (j >= loq && j < hiq) ? accs[n][r] : -1e30f;
      sv[n] = s; mx = fmaxf(mx, s);
    }
#pragma unroll
    for (int off = 1; off < 16; off <<= 1) mx = fmaxf(mx, __shfl_xor(mx, off));
    float e[8]; float se = 0.f;
#pragma unroll
    for (int n = 0; n < 8; ++n) { e[n] = __expf(sv[n] - mx); se += e[n]; }
#pragma unroll
    for (int off = 1; off < 16; off <<= 1) se += __shfl_xor(se, off);
    float inv = 1.f / se;
    int q = ghi * 4 + r;
#pragma unroll
    for (int n = 0; n < 8; ++n) {
      float pv = e[n] * inv;
      int klocal = n * 16 + rsel;
      pl[q * 128 + (((klocal >> 3) ^ (q & 7)) * 8) + (klocal & 7)] = f2bf(pv);
      if (guided) {
        int j = klo + klocal;
        float d = (float)j * (1.f / NT2) - (float)t * (1.f / NT1);
        gacc += pv * (1.f - __expf(-(d * d) * 5.5555555556f));
      }
    }
  }
  if (guided) {
    gacc = warp_sum(gacc);
    if (lane == 0) atomicAdd(gl, gacc * (1.f / 16777216.f));
  }
  __syncthreads();

  // stage VT window [192 chans][128 keys] bf16 into the K buffer (reuse)
  {
    const size_t vbase = ((size_t)(b * 2 + h) * ND) * NT2 + klo;
#pragma unroll
    for (int it = 0; it < 12; ++it) {
      int g = it * 256 + tid;
      int row = g >> 4, go = g & 15;
      int gs = go ^ (row & 7);
      GLOAD16(vtb + vbase + (size_t)row * NT2 + gs * 8, &lds[(it * 256 + wv * 64) * 8]);
    }
  }
  __syncthreads();

  // PV: P[16x128] @ V[128x192] -> O[16x192]
  f32x4 acco[12] = {};
#pragma unroll
  for (int kt = 0; kt < 4; ++kt) {
    bf16x8 pa = *(const bf16x8*)&pl[rsel * 128 + (((kt * 4 + ghi) ^ (rsel & 7)) * 8)];
#pragma unroll
    for (int n = 0; n < 12; ++n) {
      int row = n * 16 + rsel;
      bf16x8 bfr = *(const bf16x8*)&lds[row * 128 + (((kt * 4 + ghi) ^ (rsel & 7)) * 8)];
      acco[n] = __builtin_amdgcn_mfma_f32_16x16x32_bf16(pa, bfr, acco[n], 0, 0, 0);
    }
  }

  unsigned short* obase = o + (size_t)(b * NT1 + t0w + ghi * 4) * NC + h * ND;
#pragma unroll
  for (int n = 0; n < 12; ++n) {
#pragma unroll
    for (int r = 0; r < 4; ++r) {
      obase[(size_t)r * NC + n * 16 + rsel] = f2bf(acco[n][r]);
    }
  }
}

extern "C" void kernel_launch(void* const* d_in, const int* in_sizes, int n_in,
                              void* d_out, int out_size, void* d_ws, size_t ws_size,
                              hipStream_t stream) {
  (void)in_sizes; (void)n_in; (void)out_size; (void)ws_size;
  const float* x1    = (const float*)d_in[0];
  const float* x2    = (const float*)d_in[1];
  const float* alpha = (const float*)d_in[2];
  const float* ln1_g = (const float*)d_in[3];
  const float* ln1_b = (const float*)d_in[4];
  const float* qw    = (const float*)d_in[5];
  const float* kw    = (const float*)d_in[6];
  const float* vw    = (const float*)d_in[7];
  const float* ow    = (const float*)d_in[8];
  const float* ln2_g = (const float*)d_in[9];
  const float* ln2_b = (const float*)d_in[10];
  const float* cw    = (const float*)d_in[11];
  const float* cb    = (const float*)d_in[12];
  const float* lw    = (const float*)d_in[13];
  const float* lb    = (const float*)d_in[14];
  const float* lnf_g = (const float*)d_in[15];
  const float* lnf_b = (const float*)d_in[16];
  float* out = (float*)d_out;
  float* gl = out + 6291456;   // guided-loss scalar slot

  float* p = (float*)d_ws;
  float* x1a = p; p += 6291456;    // x1 state [16384,384] f32
  // bf16 region (16B-aligned)
  unsigned short* us = (unsigned short*)p;
  unsigned short* x2b  = us; us += 1572864;            // x2+pos bf16 [4096][384]
  unsigned short* tmpb = us; us += 6291456;            // LN1 out / attn out bf16
  unsigned short* ypad = us; us += 8 * TPAD * NC;      // 6316032
  unsigned short* cwpb = us; us += 2 * (size_t)NF * NKI;   // 10616832 (both layers)
  unsigned short* lwb  = us; us += 2 * (size_t)NC * NF;    // 1179648 (both layers)
  unsigned short* hb   = us; us += (size_t)16384 * NF; // 25165824
  unsigned short* qbb  = us; us += 6291456;            // q bf16 [16384][384]
  unsigned short* kbb  = us; us += 1572864;            // k bf16 [4096][384]
  unsigned short* vtb  = us; us += 1572864;            // v^T bf16 [32*192][512]
  unsigned short* qwb  = us; us += 294912;             // weights bf16 (2 layers each)
  unsigned short* kwb  = us; us += 294912;
  unsigned short* vwb  = us; us += 294912;
  unsigned short* owb  = us; us += 294912;

  hipMemsetAsync(gl, 0, sizeof(float), stream);  // atomic accumulator, re-zeroed every launch
  k_zero_guard<<<96, 256, 0, stream>>>(ypad);
  k_add_pos2<<<12288, 256, 0, stream>>>(x1, alpha, x1a, NT1, 3145728);
  k_add_pos2_bf16<<<3072, 256, 0, stream>>>(x2, alpha, x2b, NT2, 786432);

  const float scaling = 0.07216878364870323f;   // 192^-0.5
  // weight conversions, both layers, hoisted
  k_cvt_scale<<<1152, 256, 0, stream>>>(qw, qwb, 294912, scaling);
  k_cvt_scale<<<1152, 256, 0, stream>>>(kw, kwb, 294912, 1.f);
  k_cvt_scale<<<1152, 256, 0, stream>>>(vw, vwb, 294912, 1.f);
  k_cvt_scale<<<1152, 256, 0, stream>>>(ow, owb, 294912, 1.f);
  k_cvt_scale<<<4608, 256, 0, stream>>>(lw, lwb, 1179648, 1.f);
  k_pack_cw2<<<3072, 256, 0, stream>>>(cw, cwpb);

  for (int l = 0; l < 2; ++l) {
    k_ln_bf16<<<4096, 256, 0, stream>>>(x1a, ln1_g + l * 384, ln1_b + l * 384, tmpb);
    k_pgemm_mfma<<<dim3(3, 128), 256, 0, stream>>>(tmpb, qwb + (size_t)l * 147456, qbb, nullptr, 384, 0);
    k_pgemm_mfma<<<dim3(3, 32), 256, 0, stream>>>(x2b, kwb + (size_t)l * 147456, kbb, nullptr, 384, 0);
    k_pgemm_mfma<<<dim3(3, 32), 256, 0, stream>>>(x2b, vwb + (size_t)l * 147456, vtb, nullptr, 384, 2);
    k_attn_mfma<<<512, 256, 0, stream>>>(qbb, kbb, vtb, tmpb, l == 0 ? 1 : 0, gl);
    k_pgemm_mfma<<<dim3(3, 128), 256, 0, stream>>>(tmpb, owb + (size_t)l * 147456, nullptr, x1a, 384, 1);
    // FFN: ln2 -> bf16 padded, conv implicit GEMM (dbuf BK=32, 2 blocks/CU), linear (MFMA)
    k_ln_bf16p<<<4096, 256, 0, stream>>>(x1a, ln2_g + l * 384, ln2_b + l * 384, ypad);
    k_conv_mfma<<<dim3(64, 12), 512, 0, stream>>>(ypad, cwpb + (size_t)l * 5308416, cb + l * 1536, hb);
    k_lin_mfma<<<dim3(3, 128), 256, 0, stream>>>(hb, lwb + (size_t)l * 589824, lb + l * 384, x1a);
  }
  k_ln<<<4096, 256, 0, stream>>>(x1a, lnf_g, lnf_b, out, 16384);
}

// Round 6
// 778.275 us; speedup vs baseline: 1.0184x; 1.0033x over previous
//
#include <hip/hip_runtime.h>
#include <math.h>

#define NB 8
#define NT1 2048
#define NT2 512
#define NC 384
#define ND 192
#define NF 1536
#define NKI 3456   // 9*384 implicit-GEMM K for conv
#define TPAD 2056  // 2048 + 4 guard rows top and bottom

typedef __attribute__((ext_vector_type(8))) short bf16x8;
typedef __attribute__((ext_vector_type(4))) float f32x4;

#define GLOAD16(gsrc, ldst) \
  __builtin_amdgcn_global_load_lds((const __attribute__((address_space(1))) void*)(gsrc), \
                                   (__attribute__((address_space(3))) void*)(ldst), 16, 0, 0)

static __device__ __forceinline__ unsigned short f2bf(float f) {
  unsigned int u = __float_as_uint(f);
  unsigned int r = (u + 0x7fffu + ((u >> 16) & 1u)) >> 16;
  return (unsigned short)r;
}

static __device__ __forceinline__ float warp_sum(float v) {
#pragma unroll
  for (int off = 32; off > 0; off >>= 1) v += __shfl_xor(v, off);
  return v;
}

// x += alpha * sin-pos; thread handles (t,j) pair: sin at c=j, cos at c=j+192
__global__ __launch_bounds__(256) void k_add_pos2(const float* __restrict__ x,
    const float* __restrict__ alpha_p, float* __restrict__ y, int T, int total2) {
  int i = blockIdx.x * 256 + threadIdx.x;
  if (i >= total2) return;
  int j = i % 192;
  int row = i / 192;
  int t = row % T;
  float freq = __expf(-0.0482216773f * (float)j);   // ln(10000)/191
  float ang = (float)(t + 1) * freq;
  float sn, cs;
  __sincosf(ang, &sn, &cs);
  float a = alpha_p[0];
  size_t base = (size_t)row * NC;
  y[base + j] = x[base + j] + a * sn;
  y[base + j + 192] = x[base + j + 192] + a * cs;
}

__global__ __launch_bounds__(256) void k_add_pos2_bf16(const float* __restrict__ x,
    const float* __restrict__ alpha_p, unsigned short* __restrict__ y, int T, int total2) {
  int i = blockIdx.x * 256 + threadIdx.x;
  if (i >= total2) return;
  int j = i % 192;
  int row = i / 192;
  int t = row % T;
  float freq = __expf(-0.0482216773f * (float)j);
  float ang = (float)(t + 1) * freq;
  float sn, cs;
  __sincosf(ang, &sn, &cs);
  float a = alpha_p[0];
  size_t base = (size_t)row * NC;
  y[base + j] = f2bf(x[base + j] + a * sn);
  y[base + j + 192] = f2bf(x[base + j + 192] + a * cs);
}

// LayerNorm over last dim (384). One wave per row. fp32 out (final LN).
__global__ __launch_bounds__(256) void k_ln(const float* __restrict__ x,
    const float* __restrict__ g, const float* __restrict__ b,
    float* __restrict__ y, int nrows) {
  int row = blockIdx.x * 4 + (threadIdx.x >> 6);
  int lane = threadIdx.x & 63;
  if (row >= nrows) return;
  const float* xr = x + (size_t)row * NC;
  float v[6];
  float s = 0.f, s2 = 0.f;
#pragma unroll
  for (int i = 0; i < 6; ++i) {
    float t = xr[lane + 64 * i];
    v[i] = t; s += t; s2 += t * t;
  }
  s = warp_sum(s); s2 = warp_sum(s2);
  float mean = s * (1.f / NC);
  float var = s2 * (1.f / NC) - mean * mean;
  float rs = rsqrtf(var + 1e-5f);
  float* yr = y + (size_t)row * NC;
#pragma unroll
  for (int i = 0; i < 6; ++i) {
    int cc = lane + 64 * i;
    yr[cc] = (v[i] - mean) * rs * g[cc] + b[cc];
  }
}

// LayerNorm -> bf16 (unpadded), feeds MFMA projections
__global__ __launch_bounds__(256) void k_ln_bf16(const float* __restrict__ x,
    const float* __restrict__ g, const float* __restrict__ b,
    unsigned short* __restrict__ y) {
  int row = blockIdx.x * 4 + (threadIdx.x >> 6);
  int lane = threadIdx.x & 63;
  const float* xr = x + (size_t)row * NC;
  float v[6];
  float s = 0.f, s2 = 0.f;
#pragma unroll
  for (int i = 0; i < 6; ++i) {
    float t = xr[lane + 64 * i];
    v[i] = t; s += t; s2 += t * t;
  }
  s = warp_sum(s); s2 = warp_sum(s2);
  float mean = s * (1.f / NC);
  float var = s2 * (1.f / NC) - mean * mean;
  float rs = rsqrtf(var + 1e-5f);
  unsigned short* yr = y + (size_t)row * NC;
#pragma unroll
  for (int i = 0; i < 6; ++i) {
    int cc = lane + 64 * i;
    yr[cc] = f2bf((v[i] - mean) * rs * g[cc] + b[cc]);
  }
}

// LayerNorm -> bf16 into guard-padded [8][2056][384] buffer (row t -> t+4)
__global__ __launch_bounds__(256) void k_ln_bf16p(const float* __restrict__ x,
    const float* __restrict__ g, const float* __restrict__ b,
    unsigned short* __restrict__ ypad) {
  int row = blockIdx.x * 4 + (threadIdx.x >> 6);
  int lane = threadIdx.x & 63;
  const float* xr = x + (size_t)row * NC;
  float v[6];
  float s = 0.f, s2 = 0.f;
#pragma unroll
  for (int i = 0; i < 6; ++i) {
    float t = xr[lane + 64 * i];
    v[i] = t; s += t; s2 += t * t;
  }
  s = warp_sum(s); s2 = warp_sum(s2);
  float mean = s * (1.f / NC);
  float var = s2 * (1.f / NC) - mean * mean;
  float rs = rsqrtf(var + 1e-5f);
  int bb = row >> 11, t = row & 2047;
  unsigned short* yr = ypad + ((size_t)(bb * TPAD + t + 4)) * NC;
#pragma unroll
  for (int i = 0; i < 6; ++i) {
    int cc = lane + 64 * i;
    yr[cc] = f2bf((v[i] - mean) * rs * g[cc] + b[cc]);
  }
}

// zero the 4 guard rows top+bottom of each batch slab in ypad
__global__ __launch_bounds__(256) void k_zero_guard(unsigned short* __restrict__ ypad) {
  int i = blockIdx.x * 256 + threadIdx.x;   // 8*8*384 = 24576
  if (i >= 24576) return;
  int c = i % NC;
  int r = (i / NC) % 8;
  int b = i / (NC * 8);
  int t = (r < 4) ? r : (2048 + r);         // rows 0..3 and 2052..2055
  ypad[((size_t)b * TPAD + t) * NC + c] = 0;
}

// pack + convert cw[f][c][kk] -> cwp[f][kk*384+c] bf16. One block per f-row,
// coalesced load -> LDS -> coalesced store (LDS read stride 9: conflict-free).
__global__ __launch_bounds__(256) void k_pack_cw2(const float* __restrict__ cw,
    unsigned short* __restrict__ cwp) {
  __shared__ float s[NKI];
  int f = blockIdx.x;
  const float* src = cw + (size_t)f * NKI;
  for (int i = threadIdx.x; i < NKI; i += 256) s[i] = src[i];
  __syncthreads();
  unsigned short* dst = cwp + (size_t)f * NKI;
  for (int i = threadIdx.x; i < NKI; i += 256) {
    int kk = i / NC, cc = i - kk * NC;
    dst[i] = f2bf(s[cc * 9 + kk]);
  }
}

// fused qkvo weight convert: dst = [qwb|kwb|vwb|owb] contiguous, q scaled
__global__ __launch_bounds__(256) void k_cvt_qkvo(const float* __restrict__ qw,
    const float* __restrict__ kw, const float* __restrict__ vw,
    const float* __restrict__ ow, unsigned short* __restrict__ dst, float qscale) {
  int i = blockIdx.x * 256 + threadIdx.x;
  if (i >= 4 * 294912) return;
  int w = i / 294912;
  int j = i - w * 294912;
  const float* s = (w == 0) ? qw : (w == 1) ? kw : (w == 2) ? vw : ow;
  float sc = (w == 0) ? qscale : 1.f;
  dst[i] = f2bf(s[j] * sc);
}

// fp32 -> bf16 plain
__global__ __launch_bounds__(256) void k_cvt(const float* __restrict__ x,
    unsigned short* __restrict__ y, int n) {
  int i = blockIdx.x * 256 + threadIdx.x;
  if (i < n) y[i] = f2bf(x[i]);
}

// Projection GEMM: A[M,K]bf16 @ W[N=384,K]bf16^T. 128x128 tile, m97 structure.
// mode 0: bf16 row write to Cb. mode 1: Cf += acc (fused residual, o-proj).
__global__ __launch_bounds__(256) void k_pgemm_mfma(
    const unsigned short* __restrict__ A,
    const unsigned short* __restrict__ W,
    unsigned short* __restrict__ Cb,
    float* __restrict__ Cf,
    int K, int mode) {
  __shared__ unsigned short As[128 * 32];
  __shared__ unsigned short Bs[128 * 32];
  const int bn = blockIdx.x * 128;
  const int bm = blockIdx.y * 128;
  const int tid = threadIdx.x;
  const int lane = tid & 63, wv = tid >> 6;
  const int wr = (wv >> 1) * 64, wc = (wv & 1) * 64;
  f32x4 acc[4][4] = {};

  const int chunk = wv * 2;
  const int rloc = chunk * 16 + (lane >> 2);
  const int slot = (lane & 3) * 8;
  const size_t abase = ((size_t)(bm + rloc)) * K + slot;
  const size_t bbase = ((size_t)(bn + rloc)) * K + slot;
  unsigned short* AsW0 = &As[chunk * 512];
  unsigned short* AsW1 = &As[(chunk + 1) * 512];
  unsigned short* BsW0 = &Bs[chunk * 512];
  unsigned short* BsW1 = &Bs[(chunk + 1) * 512];

  const int rsel = lane & 15, ksel = (lane >> 4) * 8;

  for (int kt = 0; kt < K; kt += 32) {
    GLOAD16(A + abase + kt, AsW0);
    GLOAD16(A + abase + kt + (size_t)16 * K, AsW1);
    GLOAD16(W + bbase + kt, BsW0);
    GLOAD16(W + bbase + kt + (size_t)16 * K, BsW1);
    __syncthreads();
    bf16x8 af[4], bfr[4];
#pragma unroll
    for (int m = 0; m < 4; ++m)
      af[m] = *(const bf16x8*)&As[(wr + m * 16 + rsel) * 32 + ksel];
#pragma unroll
    for (int n = 0; n < 4; ++n)
      bfr[n] = *(const bf16x8*)&Bs[(wc + n * 16 + rsel) * 32 + ksel];
#pragma unroll
    for (int m = 0; m < 4; ++m)
#pragma unroll
      for (int n = 0; n < 4; ++n)
        acc[m][n] = __builtin_amdgcn_mfma_f32_16x16x32_bf16(af[m], bfr[n], acc[m][n], 0, 0, 0);
    __syncthreads();
  }

  const int col0 = bn + wc + (lane & 15);
  const int row0 = bm + wr + (lane >> 4) * 4;
#pragma unroll
  for (int m = 0; m < 4; ++m) {
#pragma unroll
    for (int n = 0; n < 4; ++n) {
      int col = col0 + n * 16;
#pragma unroll
      for (int r = 0; r < 4; ++r) {
        int row = row0 + m * 16 + r;
        if (mode == 0) {
          Cb[(size_t)row * NC + col] = f2bf(acc[m][n][r]);
        } else {
          size_t oi = (size_t)row * NC + col;
          Cf[oi] = acc[m][n][r] + Cf[oi];
        }
      }
    }
  }
}

// Fused K and V projections (z=0: k -> kbb row layout; z=1: v -> vtb transposed)
__global__ __launch_bounds__(256) void k_pgemm_kv(
    const unsigned short* __restrict__ A,
    const unsigned short* __restrict__ Wk,
    const unsigned short* __restrict__ Wv,
    unsigned short* __restrict__ Kb,
    unsigned short* __restrict__ Vtb) {
  __shared__ unsigned short As[128 * 32];
  __shared__ unsigned short Bs[128 * 32];
  const int z = blockIdx.z;
  const unsigned short* W = z ? Wv : Wk;
  const int bn = blockIdx.x * 128;
  const int bm = blockIdx.y * 128;
  const int tid = threadIdx.x;
  const int lane = tid & 63, wv = tid >> 6;
  const int wr = (wv >> 1) * 64, wc = (wv & 1) * 64;
  f32x4 acc[4][4] = {};

  const int chunk = wv * 2;
  const int rloc = chunk * 16 + (lane >> 2);
  const int slot = (lane & 3) * 8;
  const size_t abase = ((size_t)(bm + rloc)) * NC + slot;
  const size_t bbase = ((size_t)(bn + rloc)) * NC + slot;
  unsigned short* AsW0 = &As[chunk * 512];
  unsigned short* AsW1 = &As[(chunk + 1) * 512];
  unsigned short* BsW0 = &Bs[chunk * 512];
  unsigned short* BsW1 = &Bs[(chunk + 1) * 512];

  const int rsel = lane & 15, ksel = (lane >> 4) * 8;

  for (int kt = 0; kt < NC; kt += 32) {
    GLOAD16(A + abase + kt, AsW0);
    GLOAD16(A + abase + kt + (size_t)16 * NC, AsW1);
    GLOAD16(W + bbase + kt, BsW0);
    GLOAD16(W + bbase + kt + (size_t)16 * NC, BsW1);
    __syncthreads();
    bf16x8 af[4], bfr[4];
#pragma unroll
    for (int m = 0; m < 4; ++m)
      af[m] = *(const bf16x8*)&As[(wr + m * 16 + rsel) * 32 + ksel];
#pragma unroll
    for (int n = 0; n < 4; ++n)
      bfr[n] = *(const bf16x8*)&Bs[(wc + n * 16 + rsel) * 32 + ksel];
#pragma unroll
    for (int m = 0; m < 4; ++m)
#pragma unroll
      for (int n = 0; n < 4; ++n)
        acc[m][n] = __builtin_amdgcn_mfma_f32_16x16x32_bf16(af[m], bfr[n], acc[m][n], 0, 0, 0);
    __syncthreads();
  }

  const int col0 = bn + wc + (lane & 15);
  const int row0 = bm + wr + (lane >> 4) * 4;
#pragma unroll
  for (int m = 0; m < 4; ++m) {
#pragma unroll
    for (int n = 0; n < 4; ++n) {
      int col = col0 + n * 16;
#pragma unroll
      for (int r = 0; r < 4; ++r) {
        int row = row0 + m * 16 + r;
        if (z == 0) {
          Kb[(size_t)row * NC + col] = f2bf(acc[m][n][r]);
        } else {
          // vtb[(b*384 + col)*512 + j], b = row>>9, j = row&511
          Vtb[((size_t)((row >> 9) * 384 + col)) * 512 + (row & 511)] = f2bf(acc[m][n][r]);
        }
      }
    }
  }
}

// Conv1d(C->4C,k=9,SAME) implicit GEMM. 256x128 tile, BK=64, 8 waves (4Mx2N,
// per-wave 64x64), 3-buffer LDS ring (144 KB): stage(t+2) never touches the
// buffer being read, so reads+MFMA are compiler-interleaved with NO manual
// lgkmcnt between them. Counted vmcnt(12) covers 2 iterations (~1400cy > HBM).
// Granule-XOR swizzle (pre-swizzled global src + XOR'd ds_read): conflict-free.
// Fused (+cb)*9^-0.5 -> gelu(exact) -> bf16 store.
__global__ __launch_bounds__(512) void k_conv_mfma(
    const unsigned short* __restrict__ Ypad,
    const unsigned short* __restrict__ Wp,
    const float* __restrict__ cb,
    unsigned short* __restrict__ H) {
  __shared__ unsigned short As[3][256 * 64];   // 96 KB
  __shared__ unsigned short Bs[3][128 * 64];   // 48 KB
  const int bm = blockIdx.x * 256;             // natural order: XCD = id%8 keeps A L2-hot
  const int bn = blockIdx.y * 128;
  const int b = bm >> 11, t0 = bm & 2047;
  const int tid = threadIdx.x;
  const int lane = tid & 63, wv = tid >> 6;
  const int wvM = wv >> 1, wvN = wv & 1;
  const int rsel = lane & 15, ghi = lane >> 4;
  const int l8 = lane >> 3, g8 = lane & 7;
  const int gsrc = (g8 ^ l8) * 8;              // pre-swizzled source granule (shorts)

  f32x4 acc[4][4] = {};

  const size_t arow0 = (size_t)(b * TPAD + t0 + wv * 32 + l8);   // A stage rows (wave)
  const size_t brow0 = (size_t)(bn + wv * 16 + l8);              // B stage rows (wave)

  // 6 loads/thread/tile: A 4 (32 rows), B 2 (16 rows)
#define CONV_STAGE(T, RB)                                                     \
  {                                                                           \
    const int kt_ = (T) * 64;                                                 \
    const int kk_ = kt_ / NC;                                                 \
    const int c0_ = kt_ - kk_ * NC;                                           \
    const size_t asrc_ = (arow0 + kk_) * NC + c0_ + gsrc;                     \
    GLOAD16(Ypad + asrc_, &As[RB][(wv * 32) * 64]);                           \
    GLOAD16(Ypad + asrc_ + (size_t)8 * NC, &As[RB][(wv * 32 + 8) * 64]);      \
    GLOAD16(Ypad + asrc_ + (size_t)16 * NC, &As[RB][(wv * 32 + 16) * 64]);    \
    GLOAD16(Ypad + asrc_ + (size_t)24 * NC, &As[RB][(wv * 32 + 24) * 64]);    \
    const size_t bsrc_ = brow0 * NKI + kt_ + gsrc;                            \
    GLOAD16(Wp + bsrc_, &Bs[RB][(wv * 16) * 64]);                             \
    GLOAD16(Wp + bsrc_ + (size_t)8 * NKI, &Bs[RB][(wv * 16 + 8) * 64]);       \
  }

  const int arow = wvM * 64;
  const int brow = wvN * 64;

  // One iteration: RC = ring slot of tile T (read), RS = slot of T+2 (stage)
#define CONV_ITER(T, RC, RS)                                                  \
  {                                                                           \
    if ((T) + 2 < 54) {                                                       \
      CONV_STAGE((T) + 2, RS);                                                \
      asm volatile("s_waitcnt vmcnt(12)" ::: "memory");                       \
    } else if ((T) + 1 < 54) {                                                \
      asm volatile("s_waitcnt vmcnt(6)" ::: "memory");                        \
    } else {                                                                  \
      asm volatile("s_waitcnt vmcnt(0)" ::: "memory");                        \
    }                                                                         \
    __builtin_amdgcn_sched_barrier(0);                                        \
    __builtin_amdgcn_s_barrier();          /* tile T resident in all waves */ \
    bf16x8 af[4][2], bfr[4][2];                                               \
    _Pragma("unroll")                                                         \
    for (int m = 0; m < 4; ++m) {                                             \
      int r = arow + m * 16 + rsel;                                           \
      _Pragma("unroll")                                                       \
      for (int k = 0; k < 2; ++k)                                             \
        af[m][k] = *(const bf16x8*)&As[RC][r * 64 + (((k * 4 + ghi) ^ (r & 7)) * 8)]; \
    }                                                                         \
    _Pragma("unroll")                                                         \
    for (int n = 0; n < 4; ++n) {                                             \
      int r = brow + n * 16 + rsel;                                           \
      _Pragma("unroll")                                                       \
      for (int k = 0; k < 2; ++k)                                             \
        bfr[n][k] = *(const bf16x8*)&Bs[RC][r * 64 + (((k * 4 + ghi) ^ (r & 7)) * 8)]; \
    }                                                                         \
    _Pragma("unroll")                                                         \
    for (int k = 0; k < 2; ++k)                                               \
      _Pragma("unroll")                                                       \
      for (int m = 0; m < 4; ++m)                                             \
        _Pragma("unroll")                                                     \
        for (int n = 0; n < 4; ++n)                                           \
          acc[m][n] = __builtin_amdgcn_mfma_f32_16x16x32_bf16(af[m][k], bfr[n][k], acc[m][n], 0, 0, 0); \
    asm volatile("s_waitcnt lgkmcnt(0)" ::: "memory");  /* reads of RC done */ \
    __builtin_amdgcn_sched_barrier(0);                                        \
    __builtin_amdgcn_s_barrier();          /* RC now safe to overwrite */     \
  }

  // prologue: tiles 0,1 staged; own tile-0 loads landed (6 of tile 1 in flight)
  CONV_STAGE(0, 0);
  CONV_STAGE(1, 1);
  asm volatile("s_waitcnt vmcnt(6)" ::: "memory");
  __builtin_amdgcn_sched_barrier(0);
  __builtin_amdgcn_s_barrier();

  for (int t3 = 0; t3 < 54; t3 += 3) {
    CONV_ITER(t3 + 0, 0, 2);
    CONV_ITER(t3 + 1, 1, 0);
    CONV_ITER(t3 + 2, 2, 1);
  }
#undef CONV_ITER
#undef CONV_STAGE

  const int col0 = bn + wvN * 64 + rsel;
  const int row0 = bm + wvM * 64 + ghi * 4;
#pragma unroll
  for (int m = 0; m < 4; ++m) {
#pragma unroll
    for (int n = 0; n < 4; ++n) {
      int col = col0 + n * 16;
      float cbv = cb[col];
#pragma unroll
      for (int r = 0; r < 4; ++r) {
        int row = row0 + m * 16 + r;
        float xv = (acc[m][n][r] + cbv) * 0.33333333333333333f;
        float ge = 0.5f * xv * (1.f + erff(xv * 0.70710678118654752f));
        H[(size_t)row * NF + col] = f2bf(ge);
      }
    }
  }
}

// FFN linear: x1a[m][n] += H[m][:]@lw[n][:] + lb[n].  bf16 MFMA, m97 structure.
__global__ __launch_bounds__(256) void k_lin_mfma(
    const unsigned short* __restrict__ H,
    const unsigned short* __restrict__ Wb,
    const float* __restrict__ lb,
    float* __restrict__ x1a) {
  __shared__ unsigned short As[128 * 32];
  __shared__ unsigned short Bs[128 * 32];
  const int bn = blockIdx.x * 128;
  const int bm = blockIdx.y * 128;
  const int tid = threadIdx.x;
  const int lane = tid & 63, wv = tid >> 6;
  const int wr = (wv >> 1) * 64, wc = (wv & 1) * 64;
  f32x4 acc[4][4] = {};

  const int chunk = wv * 2;
  const int rloc = chunk * 16 + (lane >> 2);
  const int slot = (lane & 3) * 8;
  const size_t abase = ((size_t)(bm + rloc)) * NF + slot;
  const size_t bbase = ((size_t)(bn + rloc)) * NF + slot;
  unsigned short* AsW0 = &As[chunk * 512];
  unsigned short* AsW1 = &As[(chunk + 1) * 512];
  unsigned short* BsW0 = &Bs[chunk * 512];
  unsigned short* BsW1 = &Bs[(chunk + 1) * 512];

  const int rsel = lane & 15, ksel = (lane >> 4) * 8;

  for (int kt = 0; kt < NF; kt += 32) {
    GLOAD16(H + abase + kt, AsW0);
    GLOAD16(H + abase + kt + (size_t)16 * NF, AsW1);
    GLOAD16(Wb + bbase + kt, BsW0);
    GLOAD16(Wb + bbase + kt + (size_t)16 * NF, BsW1);
    __syncthreads();
    bf16x8 af[4], bfr[4];
#pragma unroll
    for (int m = 0; m < 4; ++m)
      af[m] = *(const bf16x8*)&As[(wr + m * 16 + rsel) * 32 + ksel];
#pragma unroll
    for (int n = 0; n < 4; ++n)
      bfr[n] = *(const bf16x8*)&Bs[(wc + n * 16 + rsel) * 32 + ksel];
#pragma unroll
    for (int m = 0; m < 4; ++m)
#pragma unroll
      for (int n = 0; n < 4; ++n)
        acc[m][n] = __builtin_amdgcn_mfma_f32_16x16x32_bf16(af[m], bfr[n], acc[m][n], 0, 0, 0);
    __syncthreads();
  }

  const int col0 = bn + wc + (lane & 15);
  const int row0 = bm + wr + (lane >> 4) * 4;
#pragma unroll
  for (int m = 0; m < 4; ++m) {
#pragma unroll
    for (int n = 0; n < 4; ++n) {
      int col = col0 + n * 16;
      float lbv = lb[col];
#pragma unroll
      for (int r = 0; r < 4; ++r) {
        int row = row0 + m * 16 + r;
        size_t oi = (size_t)row * NC + col;
        x1a[oi] = acc[m][n][r] + lbv + x1a[oi];
      }
    }
  }
}

// Windowed cross-attention, MFMA flash-style. bf16 output (feeds o-projection).
__global__ __launch_bounds__(256) void k_attn_mfma(
    const unsigned short* __restrict__ qbb,   // [8*2048][384] bf16 (q*scaling folded in W)
    const unsigned short* __restrict__ kbb,   // [8*512][384] bf16
    const unsigned short* __restrict__ vtb,   // [(b*2+h)*192+d][512] bf16
    unsigned short* __restrict__ o, int guided, float* __restrict__ gl) {
  __shared__ unsigned short lds[32768];
  const int tid = threadIdx.x;
  const int lane = tid & 63, wv = tid >> 6;
  const int rsel = lane & 15, ghi = lane >> 4;
  const int idx = blockIdx.x;
  const int tg = idx & 31;
  const int bh = idx >> 5;
  const int h = bh & 1, b = bh >> 1;
  const int t0 = tg * 64;
  const int c0 = t0 >> 2;
  int klo = c0 - 51; if (klo < 0) klo = 0;
  klo &= ~7;                       // 16B-align for global_load_lds on vtb
  if (klo > 384) klo = 384;        // keep window inside [0,512)

  // Q fragments: A-operand layout, row = lane&15, k = ghi*8 (+32 per step)
  const unsigned short* qrow = qbb + (size_t)(b * NT1 + t0 + wv * 16 + rsel) * NC + h * ND;
  bf16x8 qf[6];
#pragma unroll
  for (int kk = 0; kk < 6; ++kk)
    qf[kk] = *(const bf16x8*)(qrow + kk * 32 + ghi * 8);

  // stage K window [128 keys][192] bf16, source pre-swizzled (granule ^ row&7)
  {
    const size_t kbase = (size_t)(b * NT2 + klo) * NC + h * ND;
#pragma unroll
    for (int it = 0; it < 12; ++it) {
      int g = it * 256 + tid;
      int row = g / 24, go = g % 24;
      int gs = go ^ (row & 7);
      GLOAD16(kbb + kbase + (size_t)row * NC + gs * 8, &lds[(it * 256 + wv * 64) * 8]);
    }
  }
  __syncthreads();

  // QK^T: 16 queries x 128 keys per wave
  f32x4 accs[8] = {};
#pragma unroll
  for (int kk = 0; kk < 6; ++kk) {
#pragma unroll
    for (int n = 0; n < 8; ++n) {
      int row = n * 16 + rsel;
      bf16x8 bfr = *(const bf16x8*)&lds[row * 192 + (((kk * 4 + ghi) ^ (rsel & 7)) * 8)];
      accs[n] = __builtin_amdgcn_mfma_f32_16x16x32_bf16(qf[kk], bfr, accs[n], 0, 0, 0);
    }
  }

  // masked softmax per query row; rows live on 16-lane groups (row=ghi*4+r, col=rsel)
  unsigned short* pl = &lds[24576 + wv * 2048];
  float gacc = 0.f;
  const int t0w = t0 + wv * 16;
#pragma unroll
  for (int r = 0; r < 4; ++r) {
    int t = t0w + ghi * 4 + r;
    int c = t >> 2;
    int loq = c - 51; if (loq < 0) loq = 0;
    int hiq = c + 51; if (hiq > NT2) hiq = NT2;
    float sv[8];
    float mx = -1e30f;
#pragma unroll
    for (int n = 0; n < 8; ++n) {
      int j = klo + n * 16 + rsel;
      float s = (j >= loq && j < hiq) ? accs[n][r] : -1e30f;
      sv[n] = s; mx = fmaxf(mx, s);
    }
#pragma unroll
    for (int off = 1; off < 16; off <<= 1) mx = fmaxf(mx, __shfl_xor(mx, off));
    float e[8]; float se = 0.f;
#pragma unroll
    for (int n = 0; n < 8; ++n) { e[n] = __expf(sv[n] - mx); se += e[n]; }
#pragma unroll
    for (int off = 1; off < 16; off <<= 1) se += __shfl_xor(se, off);
    float inv = 1.f / se;
    int q = ghi * 4 + r;
#pragma unroll
    for (int n = 0; n < 8; ++n) {
      float pv = e[n] * inv;
      int klocal = n * 16 + rsel;
      pl[q * 128 + (((klocal >> 3) ^ (q & 7)) * 8) + (klocal & 7)] = f2bf(pv);
      if (guided) {
        int j = klo + klocal;
        float d = (float)j * (1.f / NT2) - (float)t * (1.f / NT1);
        gacc += pv * (1.f - __expf(-(d * d) * 5.5555555556f));
      }
    }
  }
  if (guided) {
    gacc = warp_sum(gacc);
    if (lane == 0) atomicAdd(gl, gacc * (1.f / 16777216.f));
  }
  __syncthreads();

  // stage VT window [192 chans][128 keys] bf16 into the K buffer (reuse)
  {
    const size_t vbase = ((size_t)(b * 2 + h) * ND) * NT2 + klo;
#pragma unroll
    for (int it = 0; it < 12; ++it) {
      int g = it * 256 + tid;
      int row = g >> 4, go = g & 15;
      int gs = go ^ (row & 7);
      GLOAD16(vtb + vbase + (size_t)row * NT2 + gs * 8, &lds[(it * 256 + wv * 64) * 8]);
    }
  }
  __syncthreads();

  // PV: P[16x128] @ V[128x192] -> O[16x192]
  f32x4 acco[12] = {};
#pragma unroll
  for (int kt = 0; kt < 4; ++kt) {
    bf16x8 pa = *(const bf16x8*)&pl[rsel * 128 + (((kt * 4 + ghi) ^ (rsel & 7)) * 8)];
#pragma unroll
    for (int n = 0; n < 12; ++n) {
      int row = n * 16 + rsel;
      bf16x8 bfr = *(const bf16x8*)&lds[row * 128 + (((kt * 4 + ghi) ^ (rsel & 7)) * 8)];
      acco[n] = __builtin_amdgcn_mfma_f32_16x16x32_bf16(pa, bfr, acco[n], 0, 0, 0);
    }
  }

  unsigned short* obase = o + (size_t)(b * NT1 + t0w + ghi * 4) * NC + h * ND;
#pragma unroll
  for (int n = 0; n < 12; ++n) {
#pragma unroll
    for (int r = 0; r < 4; ++r) {
      obase[(size_t)r * NC + n * 16 + rsel] = f2bf(acco[n][r]);
    }
  }
}

extern "C" void kernel_launch(void* const* d_in, const int* in_sizes, int n_in,
                              void* d_out, int out_size, void* d_ws, size_t ws_size,
                              hipStream_t stream) {
  (void)in_sizes; (void)n_in; (void)out_size; (void)ws_size;
  const float* x1    = (const float*)d_in[0];
  const float* x2    = (const float*)d_in[1];
  const float* alpha = (const float*)d_in[2];
  const float* ln1_g = (const float*)d_in[3];
  const float* ln1_b = (const float*)d_in[4];
  const float* qw    = (const float*)d_in[5];
  const float* kw    = (const float*)d_in[6];
  const float* vw    = (const float*)d_in[7];
  const float* ow    = (const float*)d_in[8];
  const float* ln2_g = (const float*)d_in[9];
  const float* ln2_b = (const float*)d_in[10];
  const float* cw    = (const float*)d_in[11];
  const float* cb    = (const float*)d_in[12];
  const float* lw    = (const float*)d_in[13];
  const float* lb    = (const float*)d_in[14];
  const float* lnf_g = (const float*)d_in[15];
  const float* lnf_b = (const float*)d_in[16];
  float* out = (float*)d_out;
  float* gl = out + 6291456;   // guided-loss scalar slot

  float* p = (float*)d_ws;
  float* x1a = p; p += 6291456;    // x1 state [16384,384] f32
  // bf16 region (16B-aligned)
  unsigned short* us = (unsigned short*)p;
  unsigned short* x2b  = us; us += 1572864;            // x2+pos bf16 [4096][384]
  unsigned short* tmpb = us; us += 6291456;            // LN1 out / attn out bf16
  unsigned short* ypad = us; us += 8 * TPAD * NC;      // 6316032
  unsigned short* cwpb = us; us += 2 * (size_t)NF * NKI;   // 10616832 (both layers)
  unsigned short* lwb  = us; us += 2 * (size_t)NC * NF;    // 1179648 (both layers)
  unsigned short* hb   = us; us += (size_t)16384 * NF; // 25165824
  unsigned short* qbb  = us; us += 6291456;            // q bf16 [16384][384]
  unsigned short* kbb  = us; us += 1572864;            // k bf16 [4096][384]
  unsigned short* vtb  = us; us += 1572864;            // v^T bf16 [32*192][512]
  unsigned short* qwb  = us; us += 294912;             // weights bf16 (contiguous qkvo)
  unsigned short* kwb  = us; us += 294912;
  unsigned short* vwb  = us; us += 294912;
  unsigned short* owb  = us; us += 294912;

  hipMemsetAsync(gl, 0, sizeof(float), stream);  // atomic accumulator, re-zeroed every launch
  k_zero_guard<<<96, 256, 0, stream>>>(ypad);
  k_add_pos2<<<12288, 256, 0, stream>>>(x1, alpha, x1a, NT1, 3145728);
  k_add_pos2_bf16<<<3072, 256, 0, stream>>>(x2, alpha, x2b, NT2, 786432);

  const float scaling = 0.07216878364870323f;   // 192^-0.5
  // weight conversions, both layers, hoisted + fused
  k_cvt_qkvo<<<4608, 256, 0, stream>>>(qw, kw, vw, ow, qwb, scaling);
  k_cvt<<<4608, 256, 0, stream>>>(lw, lwb, 1179648);
  k_pack_cw2<<<3072, 256, 0, stream>>>(cw, cwpb);

  for (int l = 0; l < 2; ++l) {
    k_ln_bf16<<<4096, 256, 0, stream>>>(x1a, ln1_g + l * 384, ln1_b + l * 384, tmpb);
    k_pgemm_mfma<<<dim3(3, 128), 256, 0, stream>>>(tmpb, qwb + (size_t)l * 147456, qbb, nullptr, 384, 0);
    k_pgemm_kv<<<dim3(3, 32, 2), 256, 0, stream>>>(x2b, kwb + (size_t)l * 147456,
                                                   vwb + (size_t)l * 147456, kbb, vtb);
    k_attn_mfma<<<512, 256, 0, stream>>>(qbb, kbb, vtb, tmpb, l == 0 ? 1 : 0, gl);
    k_pgemm_mfma<<<dim3(3, 128), 256, 0, stream>>>(tmpb, owb + (size_t)l * 147456, nullptr, x1a, 384, 1);
    // FFN: ln2 -> bf16 padded, conv implicit GEMM (ring-3 MFMA), linear (MFMA)
    k_ln_bf16p<<<4096, 256, 0, stream>>>(x1a, ln2_g + l * 384, ln2_b + l * 384, ypad);
    k_conv_mfma<<<dim3(64, 12), 512, 0, stream>>>(ypad, cwpb + (size_t)l * 5308416, cb + l * 1536, hb);
    k_lin_mfma<<<dim3(3, 128), 256, 0, stream>>>(hb, lwb + (size_t)l * 589824, lb + l * 384, x1a);
  }
  k_ln<<<4096, 256, 0, stream>>>(x1a, lnf_g, lnf_b, out, 16384);
}